// Round 7
// baseline (3950.393 us; speedup 1.0000x reference)
//
#include <hip/hip_runtime.h>

typedef float f4 __attribute__((ext_vector_type(4)));
typedef _Float16 h8v __attribute__((ext_vector_type(8)));
typedef float f32x4 __attribute__((ext_vector_type(4)));

static constexpr int NB = 128, NT = 4096, NI = 64, NH = 256, NO = 64;
static constexpr int CPB = 16;           // chains per block (16 real MFMA columns)
static constexpr int NBLK = NB / CPB;    // 8 blocks

union I4H8 { int4 i; h8v h; };
union H2I2 { int i; _Float16 h[2]; };

__device__ __forceinline__ int pk2(float a, float b) {
    H2I2 u; u.h[0] = (_Float16)a; u.h[1] = (_Float16)b; return u.i;
}
__device__ __forceinline__ h8v pack8(f4 lo, f4 hi) {
    h8v r;
    r[0] = (_Float16)lo.x; r[1] = (_Float16)lo.y; r[2] = (_Float16)lo.z; r[3] = (_Float16)lo.w;
    r[4] = (_Float16)hi.x; r[5] = (_Float16)hi.y; r[6] = (_Float16)hi.z; r[7] = (_Float16)hi.w;
    return r;
}
__device__ __forceinline__ f32x4 mfma16(h8v a, h8v b, f32x4 c) {
    return __builtin_amdgcn_mfma_f32_16x16x32_f16(a, b, c, 0, 0, 0);
}
__device__ __forceinline__ float fast_tanh(float x) {
    float e = __builtin_amdgcn_exp2f(x * 2.885390081777927f); // 2*log2(e)
    return 1.0f - 2.0f * __builtin_amdgcn_rcpf(e + 1.0f);
}

// ---------------- one step, compile-time buffer parity PB and wave WV ----------------
// Layout (verified on HW in R6):
//   A-frag: lane l holds rows (l&15), k = 32kt + 4*(l>>4) + {0..3} u {16..19}
//   B-frag: lane l holds col (l&15), same k pattern; LDS slot = l (16B), kt-major rows of 1KB
//   D: col = l&15, row = 16mt + 4*(l>>4) + reg  ->  tanh(D) IS next-step B elem
//      (kt = R>>5 = 2*WV + (mt>>1), elem i = reg + 4*(mt&1)) in the SAME lane.
template<int WV, int PB>
__device__ __forceinline__ void rnn_step(
    const char* rb,            // hb base + l*16
    const h8v (&Ah)[4][8], const h8v (&Ax)[4][2],
    const float (&bias)[4][4],
    I4H8& bo0, I4H8& bo1,      // own B K-tiles 2WV, 2WV+1 (in regs)
    const f4 (&xcur)[4],       // x(t) f32 quads (this lane's B-frag source)
    f4 (&xnext)[4],            // dst for x(t+1) prefetch
    const float* xa,           // global ptr for x(t+1) quads (nullptr-like guard via doLoad)
    bool doLoad,
    bool lastStep, float* hf, int n, int g)
{
    // x B-frags for this step (VALU cvt from regs)
    I4H8 bx0, bx1;
    bx0.h = pack8(xcur[0], xcur[1]);
    bx1.h = pack8(xcur[2], xcur[3]);

    // issue foreign-kt reads early (6 x ds_read_b128, immediate offsets)
    int4 bf[8];
#pragma unroll
    for (int kt = 0; kt < 8; ++kt)
        if ((kt >> 1) != WV)
            bf[kt] = *(const int4*)(rb + PB * 8192 + kt * 1024);

    // issue x(t+1) global prefetch (VMEM pipe)
    if (doLoad) {
#pragma unroll
        for (int u = 0; u < 4; ++u) xnext[u] = *(const f4*)(xa + 16 * u);
    }

    // MFMAs with register-resident operands first (hide ds_read latency)
    f32x4 acc[4];
#pragma unroll
    for (int mt = 0; mt < 4; ++mt) {
        acc[mt] = mfma16(Ax[mt][0], bx0.h, f32x4{0.f, 0.f, 0.f, 0.f});
        acc[mt] = mfma16(Ax[mt][1], bx1.h, acc[mt]);
    }
#pragma unroll
    for (int mt = 0; mt < 4; ++mt) acc[mt] = mfma16(Ah[mt][2 * WV], bo0.h, acc[mt]);
#pragma unroll
    for (int mt = 0; mt < 4; ++mt) acc[mt] = mfma16(Ah[mt][2 * WV + 1], bo1.h, acc[mt]);
    // foreign K-tiles
#pragma unroll
    for (int kt = 0; kt < 8; ++kt) {
        if ((kt >> 1) != WV) {
            I4H8 u; u.i = bf[kt];
#pragma unroll
            for (int mt = 0; mt < 4; ++mt) acc[mt] = mfma16(Ah[mt][kt], u.h, acc[mt]);
        }
    }

    // tanh + D->B register permutation (no cross-lane movement)
    float th[4][4];
#pragma unroll
    for (int mt = 0; mt < 4; ++mt)
#pragma unroll
        for (int rg = 0; rg < 4; ++rg)
            th[mt][rg] = fast_tanh(acc[mt][rg] + bias[mt][rg]);

    bo0.i = int4{pk2(th[0][0], th[0][1]), pk2(th[0][2], th[0][3]),
                 pk2(th[1][0], th[1][1]), pk2(th[1][2], th[1][3])};
    bo1.i = int4{pk2(th[2][0], th[2][1]), pk2(th[2][2], th[2][3]),
                 pk2(th[3][0], th[3][1]), pk2(th[3][2], th[3][3])};

    // publish own K-tiles for other waves (2 x ds_write_b128)
    char* wb = (char*)rb + (PB ^ 1) * 8192 + (2 * WV) * 1024;
    *(int4*)wb = bo0.i;
    *(int4*)(wb + 1024) = bo1.i;

    if (lastStep) {
        // final h (f32) for the epilogue GEMV, chain-major
#pragma unroll
        for (int mt = 0; mt < 4; ++mt) {
            f4 hv; hv.x = th[mt][0]; hv.y = th[mt][1]; hv.z = th[mt][2]; hv.w = th[mt][3];
            *(f4*)(hf + n * NH + 64 * WV + 16 * mt + 4 * g) = hv;
        }
    }
    __syncthreads();
}

template<int WV>
__device__ void run_chain(
    const float* __restrict__ x, const float* __restrict__ wih,
    const float* __restrict__ whh, const float* __restrict__ bih,
    const float* __restrict__ bhh,
    char* hbB, float* hf, int b0)
{
    const int l = threadIdx.x & 63;
    const int n = l & 15;   // chain / MFMA column
    const int g = l >> 4;   // k-group

    // ---- cold: weights to registers as A-frags ----
    h8v Ah[4][8];   // Whh rows 64WV+16mt+(l&15), 8 K-tiles   (128 VGPR)
    h8v Ax[4][2];   // Wih rows, 2 K-tiles                     (32 VGPR)
    float bias[4][4];
#pragma unroll
    for (int mt = 0; mt < 4; ++mt) {
        const int row = 64 * WV + 16 * mt + (l & 15);
#pragma unroll
        for (int kt = 0; kt < 8; ++kt) {
            const f4* pr = (const f4*)(whh + (size_t)row * NH + kt * 32 + g * 4);
            Ah[mt][kt] = pack8(pr[0], pr[4]);
        }
#pragma unroll
        for (int kt = 0; kt < 2; ++kt) {
            const f4* pr = (const f4*)(wih + (size_t)row * NI + kt * 32 + g * 4);
            Ax[mt][kt] = pack8(pr[0], pr[4]);
        }
#pragma unroll
        for (int rg = 0; rg < 4; ++rg) {
            const int R = 64 * WV + 16 * mt + 4 * g + rg;
            bias[mt][rg] = bih[R] + bhh[R];
        }
    }

    // per-lane x source: quads {g, g+4, g+8, g+12} of each timestep row
    const float* xpt = x + (size_t)(b0 + n) * NT * NI + 4 * g;

    f4 xq[4], xqn[4];
#pragma unroll
    for (int u = 0; u < 4; ++u) xq[u] = *(const f4*)(xpt + 16 * u);  // t = 0

    I4H8 bo0, bo1;
    bo0.i = int4{0, 0, 0, 0};
    bo1.i = int4{0, 0, 0, 0};

    const char* rb = hbB + (size_t)(l * 16);

    __syncthreads();  // hb[0] zeroed, x(0) in regs

#pragma unroll 1
    for (int t = 0; t < NT; t += 2) {
        // step t (reads hb[0], writes hb[1]); prefetch x(t+1) (always valid: t <= NT-2)
        rnn_step<WV, 0>(rb, Ah, Ax, bias, bo0, bo1, xq, xqn,
                        xpt + (size_t)(t + 1) * NI, true,
                        false, hf, n, g);
        // step t+1 (reads hb[1], writes hb[0]); prefetch x(t+2) unless last pair
        const bool last = (t + 2 >= NT);
        rnn_step<WV, 1>(rb, Ah, Ax, bias, bo1 /*unused slot trick? no:*/, bo1, xq /*dummy*/, xq,
                        xpt, false, false, hf, n, g);  // placeholder, replaced below
        (void)last;
    }
}

// NOTE: the placeholder call above is wrong; real implementation below overrides run_chain.
// (kept single definition - see run_chain2)

template<int WV>
__device__ void run_chain2(
    const float* __restrict__ x, const float* __restrict__ wih,
    const float* __restrict__ whh, const float* __restrict__ bih,
    const float* __restrict__ bhh,
    char* hbB, float* hf, int b0)
{
    const int l = threadIdx.x & 63;
    const int n = l & 15;
    const int g = l >> 4;

    h8v Ah[4][8];
    h8v Ax[4][2];
    float bias[4][4];
#pragma unroll
    for (int mt = 0; mt < 4; ++mt) {
        const int row = 64 * WV + 16 * mt + (l & 15);
#pragma unroll
        for (int kt = 0; kt < 8; ++kt) {
            const f4* pr = (const f4*)(whh + (size_t)row * NH + kt * 32 + g * 4);
            Ah[mt][kt] = pack8(pr[0], pr[4]);
        }
#pragma unroll
        for (int kt = 0; kt < 2; ++kt) {
            const f4* pr = (const f4*)(wih + (size_t)row * NI + kt * 32 + g * 4);
            Ax[mt][kt] = pack8(pr[0], pr[4]);
        }
#pragma unroll
        for (int rg = 0; rg < 4; ++rg) {
            const int R = 64 * WV + 16 * mt + 4 * g + rg;
            bias[mt][rg] = bih[R] + bhh[R];
        }
    }

    const float* xpt = x + (size_t)(b0 + n) * NT * NI + 4 * g;

    f4 xq[4], xqn[4];
#pragma unroll
    for (int u = 0; u < 4; ++u) xq[u] = *(const f4*)(xpt + 16 * u);

    I4H8 bo0, bo1;
    bo0.i = int4{0, 0, 0, 0};
    bo1.i = int4{0, 0, 0, 0};

    const char* rb = hbB + (size_t)(l * 16);

    __syncthreads();

#pragma unroll 1
    for (int t = 0; t < NT; t += 2) {
        // ---- step t: read hb[0] -> write hb[1]; x(t) in xq; prefetch x(t+1) into xqn
        rnn_step<WV, 0>(rb, Ah, Ax, bias, bo0, bo1, xq, xqn,
                        xpt + (size_t)(t + 1) * NI, true, false, hf, n, g);
        // ---- step t+1: read hb[1] -> write hb[0]; x(t+1) in xqn; prefetch x(t+2) into xq
        const bool last = (t + 2 >= NT);
        rnn_step<WV, 1>(rb, Ah, Ax, bias, bo0, bo1, xqn, xq,
                        xpt + (size_t)(t + 2) * NI, !last, last, hf, n, g);
    }
}

__global__ __launch_bounds__(256, 1) void rnn_mfma2(
    const float* __restrict__ x, const float* __restrict__ wih,
    const float* __restrict__ whh, const float* __restrict__ bih,
    const float* __restrict__ bhh, const float* __restrict__ wy,
    const float* __restrict__ by, float* __restrict__ out)
{
    __shared__ int4 hb[2][8][64];      // [buf][kt][lane-slot], 16 KB
    __shared__ float hf[CPB * NH];     // final h f32, 16 KB

    const int tid = threadIdx.x;
    const int w = tid >> 6;
    const int b0 = blockIdx.x * CPB;

    // zero both h buffers (1024 int4 slots)
    {
        int4 z{0, 0, 0, 0};
        int4* hp = (int4*)hb;
        hp[tid] = z; hp[tid + 256] = z; hp[tid + 512] = z; hp[tid + 768] = z;
    }
    // NOTE: __syncthreads happens inside run_chain2 (every wave executes the same
    // number of barriers in the same order - AMD s_barrier counts wave arrivals).
    if (w == 0)      run_chain2<0>(x, wih, whh, bih, bhh, (char*)hb, hf, b0);
    else if (w == 1) run_chain2<1>(x, wih, whh, bih, bhh, (char*)hb, hf, b0);
    else if (w == 2) run_chain2<2>(x, wih, whh, bih, bhh, (char*)hb, hf, b0);
    else             run_chain2<3>(x, wih, whh, bih, bhh, (char*)hb, hf, b0);

    // ---- epilogue: y = h_last @ Wy^T + by ----
    const int c = tid >> 4;          // chain
    const int jo = tid & 15;
    const f4* hp = (const f4*)(hf + c * NH);
#pragma unroll
    for (int k = 0; k < 4; ++k) {
        const int o = jo + 16 * k;
        float accy = by[o];
        const f4* wr = (const f4*)(wy + (size_t)o * NH);
#pragma unroll 16
        for (int u = 0; u < NH / 4; ++u) {
            f4 wv = wr[u]; f4 hv = hp[u];
            accy += wv.x * hv.x + wv.y * hv.y + wv.z * hv.z + wv.w * hv.w;
        }
        out[(size_t)(b0 + c) * NO + o] = accy;
    }
}

extern "C" void kernel_launch(void* const* d_in, const int* in_sizes, int n_in,
                              void* d_out, int out_size, void* d_ws, size_t ws_size,
                              hipStream_t stream) {
    const float* x   = (const float*)d_in[0];
    const float* wih = (const float*)d_in[1];
    const float* whh = (const float*)d_in[2];
    const float* bih = (const float*)d_in[3];
    const float* bhh = (const float*)d_in[4];
    const float* wy  = (const float*)d_in[5];
    const float* by  = (const float*)d_in[6];
    float* out = (float*)d_out;

    rnn_mfma2<<<dim3(NBLK), dim3(256), 0, stream>>>(x, wih, whh, bih, bhh, wy, by, out);
}

// Round 8
// 3541.701 us; speedup vs baseline: 1.1154x; 1.1154x over previous
//
#include <hip/hip_runtime.h>

typedef float f4 __attribute__((ext_vector_type(4)));
typedef _Float16 h8v __attribute__((ext_vector_type(8)));
typedef _Float16 h2 __attribute__((ext_vector_type(2)));
typedef __fp16 fp16v2 __attribute__((ext_vector_type(2)));
typedef float f32x4 __attribute__((ext_vector_type(4)));

static constexpr int NB = 128, NT = 4096, NI = 64, NH = 256, NO = 64;
static constexpr int CPB = 16;           // chains per block
static constexpr int NBLK = NB / CPB;    // 8 blocks
static constexpr size_t XP_BYTES = (size_t)NB * NT * NH * 2;  // fp16 xp in d_ws

union I4H8 { int4 i; h8v h; };
union H2I2 { int i; _Float16 h[2]; };
union PKU  { fp16v2 v; int i; };

__device__ __forceinline__ int pk2(float a, float b) {
#if __has_builtin(__builtin_amdgcn_cvt_pkrtz)
    PKU u; u.v = __builtin_amdgcn_cvt_pkrtz(a, b); return u.i;
#else
    H2I2 u; u.h[0] = (_Float16)a; u.h[1] = (_Float16)b; return u.i;
#endif
}
__device__ __forceinline__ h8v pack8(f4 lo, f4 hi) {
    h8v r;
    r[0] = (_Float16)lo.x; r[1] = (_Float16)lo.y; r[2] = (_Float16)lo.z; r[3] = (_Float16)lo.w;
    r[4] = (_Float16)hi.x; r[5] = (_Float16)hi.y; r[6] = (_Float16)hi.z; r[7] = (_Float16)hi.w;
    return r;
}
__device__ __forceinline__ f32x4 mfma16(h8v a, h8v b, f32x4 c) {
    return __builtin_amdgcn_mfma_f32_16x16x32_f16(a, b, c, 0, 0, 0);
}
__device__ __forceinline__ float fast_tanh(float x) {
    float e = __builtin_amdgcn_exp2f(x * 2.885390081777927f); // 2*log2(e)
    return 1.0f - 2.0f * __builtin_amdgcn_rcpf(e + 1.0f);
}
__device__ __forceinline__ float fdot2(h2 a, h2 b, float c) {
#if __has_builtin(__builtin_amdgcn_fdot2)
    return __builtin_amdgcn_fdot2(a, b, c, false);
#else
    return c + (float)a[0] * (float)b[0] + (float)a[1] * (float)b[1];
#endif
}
__device__ __forceinline__ h2 toh2(int v) { union { int i; h2 h; } u; u.i = v; return u.h; }

// LDS-only barrier: ensure my ds ops landed, sync waves, do NOT drain vmcnt.
__device__ __forceinline__ void lds_barrier() {
    asm volatile("s_waitcnt lgkmcnt(0)\n\ts_barrier" ::: "memory");
}

// ======================= pass 1: xp = x @ Wih^T + b_ih + b_hh (fp16) =======================
// (verbatim from R5 - validated). Output: natural [B][T][H] fp16 (int2-packed pairs).
__global__ __launch_bounds__(256, 1) void xp_pre(
    const float* __restrict__ x, const float* __restrict__ wih,
    const float* __restrict__ bih, const float* __restrict__ bhh,
    int* __restrict__ xpg)
{
    __shared__ int xs[64 * 32];   // 8 KB: chunk of x, fp16 [64 t][64 i]
    __shared__ int os[64 * 128];  // 32 KB: chunk of xp, fp16 [64 t][256 j]

    const int tid = threadIdx.x;
    const int w = tid >> 6, l = tid & 63;
    const int b = blockIdx.x >> 1;
    const int t0 = (blockIdx.x & 1) * (NT / 2);

    h2 wr[4][32];
    float bs[4];
#pragma unroll
    for (int a = 0; a < 4; ++a) {
        const int j = 4 * l + a;
        const f4* src = (const f4*)(wih + (size_t)j * NI);
#pragma unroll
        for (int u = 0; u < 16; ++u) {
            f4 v = src[u];
            wr[a][2 * u]     = toh2(pk2(v.x, v.y));
            wr[a][2 * u + 1] = toh2(pk2(v.z, v.w));
        }
        bs[a] = bih[j] + bhh[j];
    }

    const float* xbase = x + ((size_t)b * NT + t0) * NI;
    const int NCH = (NT / 2) / 64;

    f4 ld[4];
#pragma unroll
    for (int k = 0; k < 4; ++k) ld[k] = ((const f4*)xbase)[tid * 4 + k];

    for (int ch = 0; ch < NCH; ++ch) {
        {
            int4 w0, w1;
            w0.x = pk2(ld[0].x, ld[0].y); w0.y = pk2(ld[0].z, ld[0].w);
            w0.z = pk2(ld[1].x, ld[1].y); w0.w = pk2(ld[1].z, ld[1].w);
            w1.x = pk2(ld[2].x, ld[2].y); w1.y = pk2(ld[2].z, ld[2].w);
            w1.z = pk2(ld[3].x, ld[3].y); w1.w = pk2(ld[3].z, ld[3].w);
            *(int4*)&xs[tid * 8] = w0;
            *(int4*)&xs[tid * 8 + 4] = w1;
        }
        __syncthreads();
        if (ch + 1 < NCH) {
            const f4* nx = (const f4*)(xbase + (size_t)(ch + 1) * 64 * NI);
#pragma unroll
            for (int k = 0; k < 4; ++k) ld[k] = nx[tid * 4 + k];
        }
#pragma unroll 1
        for (int tt = 0; tt < 16; ++tt) {
            const int tl = tt * 4 + w;
            const int4* xr = (const int4*)&xs[tl * 32];
            int4 xv[8];
#pragma unroll
            for (int u = 0; u < 8; ++u) xv[u] = xr[u];
            const int* xd = (const int*)xv;
            float acc[4] = {0.f, 0.f, 0.f, 0.f};
#pragma unroll
            for (int kk = 0; kk < 32; ++kk) {
                const h2 hv = toh2(xd[kk]);
#pragma unroll
                for (int a = 0; a < 4; ++a) acc[a] = fdot2(wr[a][kk], hv, acc[a]);
            }
            int2 pk;
            pk.x = pk2(acc[0] + bs[0], acc[1] + bs[1]);
            pk.y = pk2(acc[2] + bs[2], acc[3] + bs[3]);
            *(int2*)&os[tl * 128 + l * 2] = pk;
        }
        __syncthreads();
        {
            int4* dst = (int4*)xpg + (size_t)(b * NT + t0 + ch * 64) * 32;
            const int4* s4 = (const int4*)os;
#pragma unroll
            for (int k = 0; k < 8; ++k) dst[k * 256 + tid] = s4[k * 256 + tid];
        }
        __syncthreads();
    }
}

// ======================= pass 2: recurrence, zero-shuffle MFMA =======================
// Fragment maps HW-verified in R6/R7:
//   A lane l: rows (l&15), k = 32kt + 4*(l>>4) + {0..3, 16..19}
//   B lane l: col (l&15) = chain n, same k pattern; LDS slot = l (16B), 1KB per kt
//   D lane l: col n, row R = 64w + 16mt + 4*(l>>4) + reg  ->  tanh(D) IS next-step
//      B elem (kt = 2w + (mt>>1), i = rg + 4*(mt&1)) in the SAME lane (register rename).
template<int WV, int PB>
__device__ __forceinline__ void step_zs(
    const char* rb,                       // hb base + l*16
    const h8v (&Ah)[4][8],
    I4H8& bo0, I4H8& bo1,                 // own B K-tiles 2WV, 2WV+1 (registers)
    int2 (&xq)[4],                        // xp ring slot: consumed for t, refilled for t+2
    const char* xaddr,                    // refill source (clamped)
    bool lastStep, float* hf, int n, int g)
{
    // 1) unpack xp(t) -> f32 (backend inserts counted vmcnt wait)
    float xpf[4][4];
#pragma unroll
    for (int mt = 0; mt < 4; ++mt) {
        H2I2 u0, u1; u0.i = xq[mt].x; u1.i = xq[mt].y;
        xpf[mt][0] = (float)u0.h[0]; xpf[mt][1] = (float)u0.h[1];
        xpf[mt][2] = (float)u1.h[0]; xpf[mt][3] = (float)u1.h[1];
    }
    // 2) refill ring slot for t+2 (stays in flight across barriers)
#pragma unroll
    for (int mt = 0; mt < 4; ++mt)
        xq[mt] = *(const int2*)(xaddr + mt * 32);

    // 3) foreign-kt h reads (6 x ds_read_b128)
    int4 bf[8];
#pragma unroll
    for (int kt = 0; kt < 8; ++kt)
        if ((kt >> 1) != WV) bf[kt] = *(const int4*)(rb + PB * 8192 + kt * 1024);

    // 4) 32 MFMA: own tiles first (register operands), foreign as reads land
    f32x4 acc[4];
#pragma unroll
    for (int mt = 0; mt < 4; ++mt) acc[mt] = mfma16(Ah[mt][2 * WV], bo0.h, f32x4{0.f, 0.f, 0.f, 0.f});
#pragma unroll
    for (int mt = 0; mt < 4; ++mt) acc[mt] = mfma16(Ah[mt][2 * WV + 1], bo1.h, acc[mt]);
#pragma unroll
    for (int kt = 0; kt < 8; ++kt) {
        if ((kt >> 1) != WV) {
            I4H8 u; u.i = bf[kt];
#pragma unroll
            for (int mt = 0; mt < 4; ++mt) acc[mt] = mfma16(Ah[mt][kt], u.h, acc[mt]);
        }
    }

    // 5) h(t) = tanh(acc + xp)
    float th[4][4];
#pragma unroll
    for (int mt = 0; mt < 4; ++mt)
#pragma unroll
        for (int rg = 0; rg < 4; ++rg)
            th[mt][rg] = fast_tanh(acc[mt][rg] + xpf[mt][rg]);

    // 6) D->B register rename + fp16 pack (no cross-lane movement)
    bo0.i = int4{pk2(th[0][0], th[0][1]), pk2(th[0][2], th[0][3]),
                 pk2(th[1][0], th[1][1]), pk2(th[1][2], th[1][3])};
    bo1.i = int4{pk2(th[2][0], th[2][1]), pk2(th[2][2], th[2][3]),
                 pk2(th[3][0], th[3][1]), pk2(th[3][2], th[3][3])};

    // 7) publish own K-tiles (2 x ds_write_b128)
    char* wb = (char*)rb + (PB ^ 1) * 8192 + (2 * WV) * 1024;
    *(int4*)wb = bo0.i;
    *(int4*)(wb + 1024) = bo1.i;

    if (lastStep) {
#pragma unroll
        for (int mt = 0; mt < 4; ++mt) {
            f4 hv; hv.x = th[mt][0]; hv.y = th[mt][1]; hv.z = th[mt][2]; hv.w = th[mt][3];
            *(f4*)(hf + n * NH + 64 * WV + 16 * mt + 4 * g) = hv;
        }
    }
    // 8) LDS-only barrier (no vmcnt drain)
    lds_barrier();
}

template<int WV>
__device__ void run_zs(
    const char* __restrict__ xpB,  // xp bytes
    const float* __restrict__ whh,
    char* hbB, float* hf, int b0)
{
    const int l = threadIdx.x & 63;
    const int n = l & 15;
    const int g = l >> 4;

    // cold: Whh A-frags (128 VGPR)
    h8v Ah[4][8];
#pragma unroll
    for (int mt = 0; mt < 4; ++mt) {
        const int row = 64 * WV + 16 * mt + (l & 15);
#pragma unroll
        for (int kt = 0; kt < 8; ++kt) {
            const f4* pr = (const f4*)(whh + (size_t)row * NH + kt * 32 + g * 4);
            Ah[mt][kt] = pack8(pr[0], pr[4]);
        }
    }

    // per-lane xp source: bytes of rows 64WV+16mt+4g+{0..3} in chain n's [T][H] slab
    const char* xpp = xpB + ((size_t)(b0 + n) * NT) * (NH * 2) + (size_t)(64 * WV + 4 * g) * 2;

    int2 xq0[4], xq1[4];
#pragma unroll
    for (int mt = 0; mt < 4; ++mt) {
        xq0[mt] = *(const int2*)(xpp + (size_t)0 * 512 + mt * 32);
        xq1[mt] = *(const int2*)(xpp + (size_t)1 * 512 + mt * 32);
    }

    I4H8 bo0, bo1;
    bo0.i = int4{0, 0, 0, 0};
    bo1.i = int4{0, 0, 0, 0};

    const char* rb = hbB + (size_t)(l * 16);

    __syncthreads();  // hb zeroed (cold full barrier is fine)

#pragma unroll 1
    for (int t = 0; t < NT; t += 2) {
        const int tA = (t + 2 < NT) ? (t + 2) : (NT - 1);
        step_zs<WV, 0>(rb, Ah, bo0, bo1, xq0, xpp + (size_t)tA * 512, false, hf, n, g);
        const bool last = (t + 2 >= NT);
        const int tB = (t + 3 < NT) ? (t + 3) : (NT - 1);
        step_zs<WV, 1>(rb, Ah, bo0, bo1, xq1, xpp + (size_t)tB * 512, last, hf, n, g);
    }
}

__global__ __launch_bounds__(256, 1) void rnn_zs(
    const char* __restrict__ xpB, const float* __restrict__ whh,
    const float* __restrict__ wy, const float* __restrict__ by,
    float* __restrict__ out)
{
    __shared__ int4 hb[2][8][64];      // [buf][kt][lane-slot], 16 KB
    __shared__ float hf[CPB * NH];     // final h f32, 16 KB

    const int tid = threadIdx.x;
    const int w = tid >> 6;
    const int b0 = blockIdx.x * CPB;

    {
        int4 z{0, 0, 0, 0};
        int4* hp = (int4*)hb;
        hp[tid] = z; hp[tid + 256] = z; hp[tid + 512] = z; hp[tid + 768] = z;
    }
    // barriers inside run_zs are executed uniformly by all 4 waves
    if (w == 0)      run_zs<0>(xpB, whh, (char*)hb, hf, b0);
    else if (w == 1) run_zs<1>(xpB, whh, (char*)hb, hf, b0);
    else if (w == 2) run_zs<2>(xpB, whh, (char*)hb, hf, b0);
    else             run_zs<3>(xpB, whh, (char*)hb, hf, b0);

    // epilogue: y = h_last @ Wy^T + by
    const int c = tid >> 4;
    const int jo = tid & 15;
    const f4* hp = (const f4*)(hf + c * NH);
#pragma unroll
    for (int k = 0; k < 4; ++k) {
        const int o = jo + 16 * k;
        float accy = by[o];
        const f4* wr = (const f4*)(wy + (size_t)o * NH);
#pragma unroll 16
        for (int u = 0; u < NH / 4; ++u) {
            f4 wv = wr[u]; f4 hv = hp[u];
            accy += wv.x * hv.x + wv.y * hv.y + wv.z * hv.z + wv.w * hv.w;
        }
        out[(size_t)(b0 + c) * NO + o] = accy;
    }
}

// ======================= fallback (R2 kernel, proven; used only if d_ws too small) =======================
__global__ __launch_bounds__(256, 1) void rnn_fb(
    const float* __restrict__ x, const float* __restrict__ wih,
    const float* __restrict__ whhg, const float* __restrict__ bih,
    const float* __restrict__ bhh, const float* __restrict__ wy,
    const float* __restrict__ by, float* __restrict__ out)
{
    typedef _Float16 h8t __attribute__((ext_vector_type(8)));
    __shared__ h2 hbuf[2][NH / 2];
    __shared__ h2 xbuf[2][16 * NI / 2];
    __shared__ float hfs[NH];

    const int j = threadIdx.x;
    const int b = blockIdx.x;

    h2 whr[NH / 2];
    {
        const f4* src = (const f4*)(whhg + (size_t)j * NH);
#pragma unroll
        for (int q = 0; q < NH / 4; ++q) {
            f4 v = src[q];
            whr[2 * q]     = toh2(pk2(v.x, v.y));
            whr[2 * q + 1] = toh2(pk2(v.z, v.w));
        }
    }
    h2 wir[NI / 2];
    {
        const f4* src = (const f4*)(wih + (size_t)j * NI);
#pragma unroll
        for (int q = 0; q < NI / 4; ++q) {
            f4 v = src[q];
            wir[2 * q]     = toh2(pk2(v.x, v.y));
            wir[2 * q + 1] = toh2(pk2(v.z, v.w));
        }
    }
    const float bias = bih[j] + bhh[j];
    const float* xb = x + (size_t)b * NT * NI;
    {
        f4 v = ((const f4*)xb)[j];
        xbuf[0][2 * j]     = toh2(pk2(v.x, v.y));
        xbuf[0][2 * j + 1] = toh2(pk2(v.z, v.w));
    }
    if (j < NH / 2) { h2 z; z[0] = (_Float16)0.f; z[1] = (_Float16)0.f; hbuf[0][j] = z; }
    __syncthreads();

    float hval = 0.f;
    f4 xnext;
    int p = 0;
#pragma unroll 1
    for (int t = 0; t < NT; ++t) {
        const int s = t & 15, c = t >> 4;
        if (s == 0 && t + 16 < NT) xnext = ((const f4*)(xb + (size_t)(t + 16) * NI))[j];
        float a0 = bias, a1 = 0.f, a2 = 0.f, a3 = 0.f;
        {
            const h8t* xp = (const h8t*)(&xbuf[c & 1][s * (NI / 2)]);
#pragma unroll
            for (int r = 0; r < NI / 8; ++r) {
                h8t v = xp[r];
                a0 = fdot2(__builtin_shufflevector(v, v, 0, 1), wir[4 * r + 0], a0);
                a1 = fdot2(__builtin_shufflevector(v, v, 2, 3), wir[4 * r + 1], a1);
                a2 = fdot2(__builtin_shufflevector(v, v, 4, 5), wir[4 * r + 2], a2);
                a3 = fdot2(__builtin_shufflevector(v, v, 6, 7), wir[4 * r + 3], a3);
            }
        }
        {
            const h8t* hp = (const h8t*)(&hbuf[p][0]);
#pragma unroll
            for (int r = 0; r < NH / 8; ++r) {
                h8t v = hp[r];
                a0 = fdot2(__builtin_shufflevector(v, v, 0, 1), whr[4 * r + 0], a0);
                a1 = fdot2(__builtin_shufflevector(v, v, 2, 3), whr[4 * r + 1], a1);
                a2 = fdot2(__builtin_shufflevector(v, v, 4, 5), whr[4 * r + 2], a2);
                a3 = fdot2(__builtin_shufflevector(v, v, 6, 7), whr[4 * r + 3], a3);
            }
        }
        hval = fast_tanh((a0 + a1) + (a2 + a3));
        ((_Float16*)hbuf[p ^ 1])[j] = (_Float16)hval;
        if (s == 15 && t + 1 < NT) {
            xbuf[(c + 1) & 1][2 * j]     = toh2(pk2(xnext.x, xnext.y));
            xbuf[(c + 1) & 1][2 * j + 1] = toh2(pk2(xnext.z, xnext.w));
        }
        __syncthreads();
        p ^= 1;
    }
    hfs[j] = hval;
    __syncthreads();
    if (j < NO) {
        float acc = by[j];
        const f4* wrow = (const f4*)(wy + (size_t)j * NH);
        const f4* hp = (const f4*)hfs;
#pragma unroll
        for (int q = 0; q < NH / 4; ++q) {
            f4 w = wrow[q]; f4 h = hp[q];
            acc += w.x * h.x + w.y * h.y + w.z * h.z + w.w * h.w;
        }
        out[b * NO + j] = acc;
    }
}

extern "C" void kernel_launch(void* const* d_in, const int* in_sizes, int n_in,
                              void* d_out, int out_size, void* d_ws, size_t ws_size,
                              hipStream_t stream) {
    const float* x   = (const float*)d_in[0];
    const float* wih = (const float*)d_in[1];
    const float* whh = (const float*)d_in[2];
    const float* bih = (const float*)d_in[3];
    const float* bhh = (const float*)d_in[4];
    const float* wy  = (const float*)d_in[5];
    const float* by  = (const float*)d_in[6];
    float* out = (float*)d_out;

    if (ws_size >= XP_BYTES) {
        xp_pre<<<dim3(256), dim3(256), 0, stream>>>(x, wih, bih, bhh, (int*)d_ws);
        rnn_zs<<<dim3(NBLK), dim3(256), 0, stream>>>((const char*)d_ws, whh, wy, by, out);
    } else {
        rnn_fb<<<dim3(NB), dim3(256), 0, stream>>>(x, wih, whh, bih, bhh, wy, by, out);
    }
}